// Round 1
// baseline (126.744 us; speedup 1.0000x reference)
//
#include <hip/hip_runtime.h>
#include <hip/hip_bf16.h>

#define N_TOTAL 8192
#define B_HALF  4096
#define D_DIM   256
#define BM      128
#define CSPLIT  8
#define COLS_PER_SPLIT (N_TOTAL / CSPLIT)   // 1024
#define BN      128

typedef __attribute__((ext_vector_type(8))) short  short8;   // 8 x bf16 (4 VGPRs)
typedef __attribute__((ext_vector_type(4))) float  f32x4;

// ---------------------------------------------------------------------------
// Kernel 1: row L2-normalize, fp32 -> bf16.  One block (256 thr) per row.
// ---------------------------------------------------------------------------
__global__ __launch_bounds__(256) void nrm_kernel(const float* __restrict__ z1,
                                                  const float* __restrict__ z2,
                                                  __hip_bfloat16* __restrict__ zn) {
    int row = blockIdx.x;           // 0..8191
    int tid = threadIdx.x;          // 0..255
    const float* src = (row < B_HALF) ? (z1 + (size_t)row * D_DIM)
                                      : (z2 + (size_t)(row - B_HALF) * D_DIM);
    float v  = src[tid];
    float ss = v * v;
#pragma unroll
    for (int m = 32; m >= 1; m >>= 1) ss += __shfl_xor(ss, m);
    __shared__ float wsum[4];
    if ((tid & 63) == 0) wsum[tid >> 6] = ss;
    __syncthreads();
    float total = wsum[0] + wsum[1] + wsum[2] + wsum[3];
    float inv = 1.0f / fmaxf(sqrtf(total), 1e-8f);   // matches ref: norm clamp 1e-8
    zn[(size_t)row * D_DIM + tid] = __float2bfloat16(v * inv);
}

// ---------------------------------------------------------------------------
// Kernel 2: positive-pair similarity  pos[i] = 2*dot(zn_i, zn_{i+B}).
// One block per pair i in [0,B).
// ---------------------------------------------------------------------------
__global__ __launch_bounds__(256) void pos_kernel(const __hip_bfloat16* __restrict__ zn,
                                                  float* __restrict__ pos) {
    int i   = blockIdx.x;           // 0..4095
    int tid = threadIdx.x;
    float a = __bfloat162float(zn[(size_t)i * D_DIM + tid]);
    float b = __bfloat162float(zn[(size_t)(i + B_HALF) * D_DIM + tid]);
    float p = a * b;
#pragma unroll
    for (int m = 32; m >= 1; m >>= 1) p += __shfl_xor(p, m);
    __shared__ float wsum[4];
    if ((tid & 63) == 0) wsum[tid >> 6] = p;
    __syncthreads();
    if (tid == 0) {
        float total = wsum[0] + wsum[1] + wsum[2] + wsum[3];
        pos[i]          = 2.0f * total;
        pos[i + B_HALF] = 2.0f * total;
    }
}

// ---------------------------------------------------------------------------
// Kernel 3: fused S = Zn Zn^T / T  +  per-row sum of exp(s - 2), diag excluded.
// Block = 256 thr (4 waves, 2x2 wave grid, 64x64 per wave). BM=128 rows/block.
// gridDim = (N/BM, CSPLIT); block (bi,ci) owns partials[ci][bi*BM .. +BM).
// MFMA 16x16x32 bf16; A/B frag: m(or n)=lane&15, k = 8*(lane>>4)+[0..8).
// D frag: col=lane&15, row = 4*(lane>>4)+reg  [guide m89, verified].
// ---------------------------------------------------------------------------
__global__ __launch_bounds__(256) void simexp_kernel(const __hip_bfloat16* __restrict__ zn,
                                                     float* __restrict__ partials) {
    const int bi  = blockIdx.x;           // row tile
    const int ci  = blockIdx.y;           // col split
    const int tid = threadIdx.x;
    const int lane = tid & 63;
    const int wid  = tid >> 6;            // 0..3
    const int wr   = wid >> 1;            // wave row (0..1)
    const int wc   = wid & 1;             // wave col (0..1)
    const int row_base = bi * BM + wr * 64;
    const int lrow16 = lane & 15;
    const int kgrp   = lane >> 4;         // 0..3

    float rowacc[4][4];                   // [mt][reg] exp-sums, row = mt*16+4*kgrp+reg
#pragma unroll
    for (int mt = 0; mt < 4; ++mt)
#pragma unroll
        for (int r = 0; r < 4; ++r) rowacc[mt][r] = 0.0f;

    for (int chunk = 0; chunk < COLS_PER_SPLIT / BN; ++chunk) {
        const int col_base = ci * COLS_PER_SPLIT + chunk * BN + wc * 64;

        f32x4 acc[4][4];
#pragma unroll
        for (int mt = 0; mt < 4; ++mt)
#pragma unroll
            for (int nt = 0; nt < 4; ++nt) acc[mt][nt] = (f32x4)(0.0f);

        for (int ks = 0; ks < 8; ++ks) {            // K = 256 = 8 * 32
            const int koff = ks * 32 + kgrp * 8;
            short8 a[4], b[4];
#pragma unroll
            for (int mt = 0; mt < 4; ++mt)
                a[mt] = *reinterpret_cast<const short8*>(
                    zn + (size_t)(row_base + mt * 16 + lrow16) * D_DIM + koff);
#pragma unroll
            for (int nt = 0; nt < 4; ++nt)
                b[nt] = *reinterpret_cast<const short8*>(
                    zn + (size_t)(col_base + nt * 16 + lrow16) * D_DIM + koff);
#pragma unroll
            for (int mt = 0; mt < 4; ++mt)
#pragma unroll
                for (int nt = 0; nt < 4; ++nt)
                    acc[mt][nt] = __builtin_amdgcn_mfma_f32_16x16x32_bf16(
                        a[mt], b[nt], acc[mt][nt], 0, 0, 0);
        }

        // Epilogue: e = exp(2*dot - 2); mask diagonal; reduce across 16 col-lanes.
#pragma unroll
        for (int mt = 0; mt < 4; ++mt) {
            const int grow_base = row_base + mt * 16 + 4 * kgrp;
#pragma unroll
            for (int r = 0; r < 4; ++r) {
                const int grow = grow_base + r;
                float esum = 0.0f;
#pragma unroll
                for (int nt = 0; nt < 4; ++nt) {
                    const int gcol = col_base + nt * 16 + lrow16;
                    float e = __expf(2.0f * acc[mt][nt][r] - 2.0f);
                    esum += (grow == gcol) ? 0.0f : e;
                }
                esum += __shfl_xor(esum, 1);
                esum += __shfl_xor(esum, 2);
                esum += __shfl_xor(esum, 4);
                esum += __shfl_xor(esum, 8);
                rowacc[mt][r] += esum;
            }
        }
    }

    __shared__ float red[4][64];          // [wid][row within wave]
    if (lrow16 == 0) {
#pragma unroll
        for (int mt = 0; mt < 4; ++mt)
#pragma unroll
            for (int r = 0; r < 4; ++r)
                red[wid][mt * 16 + 4 * kgrp + r] = rowacc[mt][r];
    }
    __syncthreads();
    if (tid < BM) {                        // 128 rows
        const int wrr = tid >> 6, l = tid & 63;
        float s = red[wrr * 2][l] + red[wrr * 2 + 1][l];
        partials[(size_t)ci * N_TOTAL + bi * BM + tid] = s;
    }
}

// ---------------------------------------------------------------------------
// Kernel 4a: per-row lse - pos, block-partial sums (deterministic).
// ---------------------------------------------------------------------------
__global__ __launch_bounds__(256) void lse_kernel(const float* __restrict__ partials,
                                                  const float* __restrict__ pos,
                                                  float* __restrict__ bsums) {
    int tid = threadIdx.x;
    int row = blockIdx.x * 256 + tid;
    float s = 0.0f;
#pragma unroll
    for (int c = 0; c < CSPLIT; ++c) s += partials[(size_t)c * N_TOTAL + row];
    float v = 2.0f + logf(s) - pos[row];
#pragma unroll
    for (int m = 32; m >= 1; m >>= 1) v += __shfl_xor(v, m);
    __shared__ float wsum[4];
    if ((tid & 63) == 0) wsum[tid >> 6] = v;
    __syncthreads();
    if (tid == 0) bsums[blockIdx.x] = wsum[0] + wsum[1] + wsum[2] + wsum[3];
}

// ---------------------------------------------------------------------------
// Kernel 4b: final mean.
// ---------------------------------------------------------------------------
__global__ void final_kernel(const float* __restrict__ bsums, float* __restrict__ out) {
    int tid = threadIdx.x;                // 64 threads
    float v = (tid < N_TOTAL / 256) ? bsums[tid] : 0.0f;
#pragma unroll
    for (int m = 32; m >= 1; m >>= 1) v += __shfl_xor(v, m);
    if (tid == 0) out[0] = v * (1.0f / (float)N_TOTAL);
}

// ---------------------------------------------------------------------------
extern "C" void kernel_launch(void* const* d_in, const int* in_sizes, int n_in,
                              void* d_out, int out_size, void* d_ws, size_t ws_size,
                              hipStream_t stream) {
    const float* z1 = (const float*)d_in[0];
    const float* z2 = (const float*)d_in[1];
    float* out = (float*)d_out;

    char* ws = (char*)d_ws;
    __hip_bfloat16* zn = (__hip_bfloat16*)ws;                              // 4 MB
    size_t off = (size_t)N_TOTAL * D_DIM * sizeof(__hip_bfloat16);
    float* pos = (float*)(ws + off);                                       // 32 KB
    off += (size_t)N_TOTAL * sizeof(float);
    float* partials = (float*)(ws + off);                                  // 256 KB
    off += (size_t)CSPLIT * N_TOTAL * sizeof(float);
    float* bsums = (float*)(ws + off);                                     // 128 B

    nrm_kernel<<<N_TOTAL, 256, 0, stream>>>(z1, z2, zn);
    pos_kernel<<<B_HALF, 256, 0, stream>>>(zn, pos);
    simexp_kernel<<<dim3(N_TOTAL / BM, CSPLIT), 256, 0, stream>>>(zn, partials);
    lse_kernel<<<N_TOTAL / 256, 256, 0, stream>>>(partials, pos, bsums);
    final_kernel<<<1, 64, 0, stream>>>(bsums, out);
}

// Round 2
// 71.826 us; speedup vs baseline: 1.7646x; 1.7646x over previous
//
#include <hip/hip_runtime.h>
#include <hip/hip_bf16.h>

#define N_TOTAL 8192
#define B_HALF  4096
#define D_DIM   256
#define BM      128
#define BN      128
#define CSPLIT  16
#define COLS_PER_SPLIT (N_TOTAL / CSPLIT)   // 512
#define NCHUNK  (COLS_PER_SPLIT / BN)       // 4 chunks of 128 cols
#define NTILES  (NCHUNK * 8)                // 32 tiles (8 K-steps of 32 per chunk)

typedef __attribute__((ext_vector_type(8))) short  short8;   // 8 x bf16 (4 VGPRs)
typedef __attribute__((ext_vector_type(4))) float  f32x4;

// async global->LDS, 16B per lane (dest = wave-uniform base + lane*16)
#define GLOAD16(src, dst) __builtin_amdgcn_global_load_lds( \
    (const __attribute__((address_space(1))) unsigned int*)(src), \
    (__attribute__((address_space(3))) unsigned int*)(dst), 16, 0, 0)

__device__ __forceinline__ float b2f(unsigned short u) {
    union { unsigned int i; float f; } c; c.i = ((unsigned int)u) << 16; return c.f;
}

// ---------------------------------------------------------------------------
// Kernel 1: row L2-normalize fp32 -> bf16. One WAVE per row (no barriers).
// ---------------------------------------------------------------------------
__global__ __launch_bounds__(256) void nrm_kernel(const float* __restrict__ z1,
                                                  const float* __restrict__ z2,
                                                  __hip_bfloat16* __restrict__ zn) {
    int row  = (blockIdx.x * 256 + threadIdx.x) >> 6;   // 0..8191
    int lane = threadIdx.x & 63;
    const float* src = (row < B_HALF) ? (z1 + (size_t)row * D_DIM)
                                      : (z2 + (size_t)(row - B_HALF) * D_DIM);
    float4 v = reinterpret_cast<const float4*>(src)[lane];
    float ss = v.x * v.x + v.y * v.y + v.z * v.z + v.w * v.w;
#pragma unroll
    for (int m = 32; m >= 1; m >>= 1) ss += __shfl_xor(ss, m);
    float inv = 1.0f / fmaxf(sqrtf(ss), 1e-8f);
    ushort4 o;
    { __hip_bfloat16 b = __float2bfloat16(v.x * inv); o.x = *reinterpret_cast<unsigned short*>(&b); }
    { __hip_bfloat16 b = __float2bfloat16(v.y * inv); o.y = *reinterpret_cast<unsigned short*>(&b); }
    { __hip_bfloat16 b = __float2bfloat16(v.z * inv); o.z = *reinterpret_cast<unsigned short*>(&b); }
    { __hip_bfloat16 b = __float2bfloat16(v.w * inv); o.w = *reinterpret_cast<unsigned short*>(&b); }
    reinterpret_cast<ushort4*>(zn + (size_t)row * D_DIM)[lane] = o;
}

// ---------------------------------------------------------------------------
// Kernel 2: pos[i] = 2*dot(zn_i, zn_{i+B}).  One WAVE per pair.
// ---------------------------------------------------------------------------
__global__ __launch_bounds__(256) void pos_kernel(const __hip_bfloat16* __restrict__ zn,
                                                  float* __restrict__ pos) {
    int i    = (blockIdx.x * 256 + threadIdx.x) >> 6;   // 0..4095
    int lane = threadIdx.x & 63;
    ushort4 ua = reinterpret_cast<const ushort4*>(zn + (size_t)i * D_DIM)[lane];
    ushort4 ub = reinterpret_cast<const ushort4*>(zn + (size_t)(i + B_HALF) * D_DIM)[lane];
    float p = b2f(ua.x) * b2f(ub.x) + b2f(ua.y) * b2f(ub.y)
            + b2f(ua.z) * b2f(ub.z) + b2f(ua.w) * b2f(ub.w);
#pragma unroll
    for (int m = 32; m >= 1; m >>= 1) p += __shfl_xor(p, m);
    if (lane == 0) {
        pos[i]          = 2.0f * p;
        pos[i + B_HALF] = 2.0f * p;
    }
}

// ---------------------------------------------------------------------------
// Kernel 3: fused  rowsum_i += sum_j exp(2*cos(i,j) - 2)  (diag excluded),
// m97-structure GEMM: 128x128 block tile, LDS dbuf staged via global_load_lds,
// 4 waves (2x2), 4x4 frags of mfma 16x16x32 bf16, BK=32.
// Flat tile loop: t in [0,32): chunk = t>>3 (128 cols), ks = t&7 (K-step).
// Per-chunk epilogue: exp into per-lane rowacc (no shuffles until block end).
// ---------------------------------------------------------------------------
__global__ __launch_bounds__(256, 3) void simexp_kernel(const __hip_bfloat16* __restrict__ zn,
                                                        float* __restrict__ partials) {
    __shared__ __attribute__((aligned(16))) __hip_bfloat16 lA[2][BM * 32];
    __shared__ __attribute__((aligned(16))) __hip_bfloat16 lB[2][BN * 32];
    __shared__ float red[4][64];

    const int bi  = blockIdx.x;           // row tile (64)
    const int ci  = blockIdx.y;           // col split (16)
    const int tid = threadIdx.x;
    const int lane = tid & 63;
    const int wid  = tid >> 6;
    const int wr   = wid >> 1;            // wave row 0..1
    const int wc   = wid & 1;             // wave col 0..1
    const int lrow16 = lane & 15;
    const int kgrp   = lane >> 4;         // 0..3

    const __hip_bfloat16* Abase  = zn + (size_t)bi * BM * D_DIM;
    const __hip_bfloat16* Bbase0 = zn + (size_t)ci * COLS_PER_SPLIT * D_DIM;

    // staging geometry: 512 granules of 16B per 8KB tile; this thread owns 2
    const int g0 = tid, g1 = tid + 256;
    const int aoff0 = (g0 >> 2) * D_DIM + (g0 & 3) * 8;   // elem offset in panel
    const int aoff1 = (g1 >> 2) * D_DIM + (g1 & 3) * 8;

    auto stage = [&](int t, int buf) {
        const int ko  = (t & 7) * 32;
        const __hip_bfloat16* Bb = Bbase0 + (size_t)(t >> 3) * BN * D_DIM;
        GLOAD16(Abase + aoff0 + ko, &lA[buf][g0 * 8]);
        GLOAD16(Abase + aoff1 + ko, &lA[buf][g1 * 8]);
        GLOAD16(Bb    + aoff0 + ko, &lB[buf][g0 * 8]);
        GLOAD16(Bb    + aoff1 + ko, &lB[buf][g1 * 8]);
    };

    f32x4 acc[4][4];
    float rowacc[4][4];
#pragma unroll
    for (int mt = 0; mt < 4; ++mt)
#pragma unroll
        for (int nt = 0; nt < 4; ++nt) { acc[mt][nt] = (f32x4)(0.0f); rowacc[mt][nt] = 0.0f; }

    stage(0, 0);
    __syncthreads();                       // buf0 staged (vmcnt drained)

    for (int t = 0; t < NTILES; ++t) {
        const int cur = t & 1;
        if (t + 1 < NTILES) stage(t + 1, cur ^ 1);   // async prefetch next tile

        short8 af[4], bfr[4];
#pragma unroll
        for (int mt = 0; mt < 4; ++mt)
            af[mt] = *reinterpret_cast<const short8*>(
                &lA[cur][(wr * 64 + mt * 16 + lrow16) * 32 + kgrp * 8]);
#pragma unroll
        for (int nt = 0; nt < 4; ++nt)
            bfr[nt] = *reinterpret_cast<const short8*>(
                &lB[cur][(wc * 64 + nt * 16 + lrow16) * 32 + kgrp * 8]);
#pragma unroll
        for (int mt = 0; mt < 4; ++mt)
#pragma unroll
            for (int nt = 0; nt < 4; ++nt)
                acc[mt][nt] = __builtin_amdgcn_mfma_f32_16x16x32_bf16(
                    af[mt], bfr[nt], acc[mt][nt], 0, 0, 0);

        if ((t & 7) == 7) {                // end of a chunk: exp-epilogue
            const int ch   = t >> 3;
            const int col0 = ci * COLS_PER_SPLIT + ch * BN + wc * 64;
            const bool diagchunk = (ci * NCHUNK + ch) == bi;
            if (diagchunk) {
#pragma unroll
                for (int mt = 0; mt < 4; ++mt) {
                    const int growb = bi * BM + wr * 64 + mt * 16 + 4 * kgrp;
#pragma unroll
                    for (int r = 0; r < 4; ++r) {
                        const int grow = growb + r;
                        float s = 0.0f;
#pragma unroll
                        for (int nt = 0; nt < 4; ++nt) {
                            const int gcol = col0 + nt * 16 + lrow16;
                            float e = __expf(2.0f * acc[mt][nt][r] - 2.0f);
                            s += (grow == gcol) ? 0.0f : e;
                        }
                        rowacc[mt][r] += s;
                    }
                }
            } else {
#pragma unroll
                for (int mt = 0; mt < 4; ++mt)
#pragma unroll
                    for (int r = 0; r < 4; ++r) {
                        float s = 0.0f;
#pragma unroll
                        for (int nt = 0; nt < 4; ++nt)
                            s += __expf(2.0f * acc[mt][nt][r] - 2.0f);
                        rowacc[mt][r] += s;
                    }
            }
#pragma unroll
            for (int mt = 0; mt < 4; ++mt)
#pragma unroll
                for (int nt = 0; nt < 4; ++nt) acc[mt][nt] = (f32x4)(0.0f);
        }
        __syncthreads();                   // next-tile stage landed; buf reuse safe
    }

    // block-end reduce: sum over the 16 col-lanes, then combine wc pairs in LDS
#pragma unroll
    for (int mt = 0; mt < 4; ++mt)
#pragma unroll
        for (int r = 0; r < 4; ++r) {
            float v = rowacc[mt][r];
            v += __shfl_xor(v, 1); v += __shfl_xor(v, 2);
            v += __shfl_xor(v, 4); v += __shfl_xor(v, 8);
            if (lrow16 == 0) red[wid][mt * 16 + kgrp * 4 + r] = v;
        }
    __syncthreads();
    if (tid < BM) {
        const int wrr = tid >> 6, l = tid & 63;
        partials[(size_t)ci * N_TOTAL + bi * BM + tid] = red[wrr * 2][l] + red[wrr * 2 + 1][l];
    }
}

// ---------------------------------------------------------------------------
// Kernel 4a: per-row lse - pos, block-partial sums (deterministic).
// ---------------------------------------------------------------------------
__global__ __launch_bounds__(256) void lse_kernel(const float* __restrict__ partials,
                                                  const float* __restrict__ pos,
                                                  float* __restrict__ bsums) {
    int tid = threadIdx.x;
    int row = blockIdx.x * 256 + tid;
    float s = 0.0f;
#pragma unroll
    for (int c = 0; c < CSPLIT; ++c) s += partials[(size_t)c * N_TOTAL + row];
    float v = 2.0f + logf(s) - pos[row];
#pragma unroll
    for (int m = 32; m >= 1; m >>= 1) v += __shfl_xor(v, m);
    __shared__ float wsum[4];
    if ((tid & 63) == 0) wsum[tid >> 6] = v;
    __syncthreads();
    if (tid == 0) bsums[blockIdx.x] = wsum[0] + wsum[1] + wsum[2] + wsum[3];
}

__global__ void final_kernel(const float* __restrict__ bsums, float* __restrict__ out) {
    int tid = threadIdx.x;                // 64 threads
    float v = (tid < N_TOTAL / 256) ? bsums[tid] : 0.0f;
#pragma unroll
    for (int m = 32; m >= 1; m >>= 1) v += __shfl_xor(v, m);
    if (tid == 0) out[0] = v * (1.0f / (float)N_TOTAL);
}

// ---------------------------------------------------------------------------
extern "C" void kernel_launch(void* const* d_in, const int* in_sizes, int n_in,
                              void* d_out, int out_size, void* d_ws, size_t ws_size,
                              hipStream_t stream) {
    const float* z1 = (const float*)d_in[0];
    const float* z2 = (const float*)d_in[1];
    float* out = (float*)d_out;

    char* ws = (char*)d_ws;
    __hip_bfloat16* zn = (__hip_bfloat16*)ws;                              // 4 MB
    size_t off = (size_t)N_TOTAL * D_DIM * sizeof(__hip_bfloat16);
    float* pos = (float*)(ws + off);                                       // 32 KB
    off += (size_t)N_TOTAL * sizeof(float);
    float* partials = (float*)(ws + off);                                  // 512 KB
    off += (size_t)CSPLIT * N_TOTAL * sizeof(float);
    float* bsums = (float*)(ws + off);                                     // 128 B

    nrm_kernel<<<N_TOTAL / 4, 256, 0, stream>>>(z1, z2, zn);
    pos_kernel<<<B_HALF / 4, 256, 0, stream>>>(zn, pos);
    simexp_kernel<<<dim3(N_TOTAL / BM, CSPLIT), 256, 0, stream>>>(zn, partials);
    lse_kernel<<<N_TOTAL / 256, 256, 0, stream>>>(partials, pos, bsums);
    final_kernel<<<1, 64, 0, stream>>>(bsums, out);
}

// Round 3
// 61.646 us; speedup vs baseline: 2.0560x; 1.1651x over previous
//
#include <hip/hip_runtime.h>
#include <hip/hip_bf16.h>

#define N_TOTAL 8192
#define B_HALF  4096
#define D_DIM   256
#define BM      128
#define BN      128
#define CSPLIT  16
#define COLS_PER_SPLIT (N_TOTAL / CSPLIT)   // 512
#define NCHUNK  (COLS_PER_SPLIT / BN)       // 4 chunks of 128 cols
#define NTILES  (NCHUNK * 8)                // 32 tiles (8 K-steps of 32 per chunk)

typedef __attribute__((ext_vector_type(8))) short  short8;   // 8 x bf16 (4 VGPRs)
typedef __attribute__((ext_vector_type(4))) float  f32x4;

// async global->LDS, 16B per lane (dest = wave-uniform base + lane*16)
#define GLOAD16(src, dst) __builtin_amdgcn_global_load_lds( \
    (const __attribute__((address_space(1))) unsigned int*)(src), \
    (__attribute__((address_space(3))) unsigned int*)(dst), 16, 0, 0)

__device__ __forceinline__ float b2f(unsigned short u) {
    union { unsigned int i; float f; } c; c.i = ((unsigned int)u) << 16; return c.f;
}

// ---------------------------------------------------------------------------
// Kernel 1: row L2-normalize fp32 -> bf16, scaled by sqrt(2) so that
// dot(zs_i, zs_j) = 2*cos(i,j) = s_ij directly.  One WAVE per row.
// ---------------------------------------------------------------------------
__global__ __launch_bounds__(256) void nrm_kernel(const float* __restrict__ z1,
                                                  const float* __restrict__ z2,
                                                  __hip_bfloat16* __restrict__ zn) {
    int row  = (blockIdx.x * 256 + threadIdx.x) >> 6;   // 0..8191
    int lane = threadIdx.x & 63;
    const float* src = (row < B_HALF) ? (z1 + (size_t)row * D_DIM)
                                      : (z2 + (size_t)(row - B_HALF) * D_DIM);
    float4 v = reinterpret_cast<const float4*>(src)[lane];
    float ss = v.x * v.x + v.y * v.y + v.z * v.z + v.w * v.w;
#pragma unroll
    for (int m = 32; m >= 1; m >>= 1) ss += __shfl_xor(ss, m);
    float inv = 1.4142135623730951f / fmaxf(sqrtf(ss), 1e-8f);
    ushort4 o;
    { __hip_bfloat16 b = __float2bfloat16(v.x * inv); o.x = *reinterpret_cast<unsigned short*>(&b); }
    { __hip_bfloat16 b = __float2bfloat16(v.y * inv); o.y = *reinterpret_cast<unsigned short*>(&b); }
    { __hip_bfloat16 b = __float2bfloat16(v.z * inv); o.z = *reinterpret_cast<unsigned short*>(&b); }
    { __hip_bfloat16 b = __float2bfloat16(v.w * inv); o.w = *reinterpret_cast<unsigned short*>(&b); }
    reinterpret_cast<ushort4*>(zn + (size_t)row * D_DIM)[lane] = o;
}

// ---------------------------------------------------------------------------
// Kernel 2: pos[i] = dot(zs_i, zs_{i+B}) = 2*cos.  One WAVE per pair.
// ---------------------------------------------------------------------------
__global__ __launch_bounds__(256) void pos_kernel(const __hip_bfloat16* __restrict__ zn,
                                                  float* __restrict__ pos) {
    int i    = (blockIdx.x * 256 + threadIdx.x) >> 6;   // 0..4095
    int lane = threadIdx.x & 63;
    ushort4 ua = reinterpret_cast<const ushort4*>(zn + (size_t)i * D_DIM)[lane];
    ushort4 ub = reinterpret_cast<const ushort4*>(zn + (size_t)(i + B_HALF) * D_DIM)[lane];
    float p = b2f(ua.x) * b2f(ub.x) + b2f(ua.y) * b2f(ub.y)
            + b2f(ua.z) * b2f(ub.z) + b2f(ua.w) * b2f(ub.w);
#pragma unroll
    for (int m = 32; m >= 1; m >>= 1) p += __shfl_xor(p, m);
    if (lane == 0) {
        pos[i]          = p;
        pos[i + B_HALF] = p;
    }
}

// ---------------------------------------------------------------------------
// Kernel 3: fused rowsum_i += sum_j exp(s_ij - 2) (diag excluded).
// m97-structure GEMM, 128x128 tile, LDS dbuf via global_load_lds, 4 waves.
// Bank-conflict fix (rule 21, both sides): LDS dest stays linear; the global
// SOURCE is pre-swizzled per 16B chunk (kc ^= (row>>1)&3) and the ds_read
// applies the same XOR — read-side XOR folds to per-lane const (lrow16>>1)&3.
// 16 rows then spread over 8 bank slots -> 2-way (free, m136).
// __launch_bounds__(256,4): grid 1024 = exactly 4 blocks/CU, one round.
// ---------------------------------------------------------------------------
__global__ __launch_bounds__(256, 4) void simexp_kernel(const __hip_bfloat16* __restrict__ zn,
                                                        float* __restrict__ partials) {
    __shared__ __attribute__((aligned(16))) __hip_bfloat16 lA[2][BM * 32];
    __shared__ __attribute__((aligned(16))) __hip_bfloat16 lB[2][BN * 32];
    __shared__ float red[4][64];

    const int bi  = blockIdx.x;           // row tile (64)
    const int ci  = blockIdx.y;           // col split (16)
    const int tid = threadIdx.x;
    const int lane = tid & 63;
    const int wid  = tid >> 6;
    const int wr   = wid >> 1;            // wave row 0..1
    const int wc   = wid & 1;             // wave col 0..1
    const int lrow16 = lane & 15;
    const int kgrp   = lane >> 4;         // 0..3
    // physical k-chunk offset for swizzled ds_read (per-lane constant)
    const int pk = (kgrp ^ ((lrow16 >> 1) & 3)) * 8;

    const __hip_bfloat16* Abase  = zn + (size_t)bi * BM * D_DIM;
    const __hip_bfloat16* Bbase0 = zn + (size_t)ci * COLS_PER_SPLIT * D_DIM;

    // staging geometry: granule g covers LDS row g>>2, chunk slot g&3 (16B);
    // source k-chunk is slot ^ ((row>>1)&3)  (inverse == same XOR)
    const int g0 = tid, g1 = tid + 256;
    const int r0 = g0 >> 2, kc0 = g0 & 3;
    const int r1 = g1 >> 2, kc1 = g1 & 3;
    const int aoff0 = r0 * D_DIM + (kc0 ^ ((r0 >> 1) & 3)) * 8;
    const int aoff1 = r1 * D_DIM + (kc1 ^ ((r1 >> 1) & 3)) * 8;

    auto stage = [&](int t, int buf) {
        const int ko  = (t & 7) * 32;
        const __hip_bfloat16* Bb = Bbase0 + (size_t)(t >> 3) * BN * D_DIM;
        GLOAD16(Abase + aoff0 + ko, &lA[buf][g0 * 8]);
        GLOAD16(Abase + aoff1 + ko, &lA[buf][g1 * 8]);
        GLOAD16(Bb    + aoff0 + ko, &lB[buf][g0 * 8]);
        GLOAD16(Bb    + aoff1 + ko, &lB[buf][g1 * 8]);
    };

    f32x4 acc[4][4];
    float rowacc[4][4];
#pragma unroll
    for (int mt = 0; mt < 4; ++mt)
#pragma unroll
        for (int nt = 0; nt < 4; ++nt) { acc[mt][nt] = (f32x4)(0.0f); rowacc[mt][nt] = 0.0f; }

    stage(0, 0);
    __syncthreads();                       // buf0 staged (vmcnt drained at barrier)

    for (int t = 0; t < NTILES; ++t) {
        const int cur = t & 1;
        if (t + 1 < NTILES) stage(t + 1, cur ^ 1);   // async prefetch next tile

        short8 af[4], bfr[4];
#pragma unroll
        for (int mt = 0; mt < 4; ++mt)
            af[mt] = *reinterpret_cast<const short8*>(
                &lA[cur][(wr * 64 + mt * 16 + lrow16) * 32 + pk]);
#pragma unroll
        for (int nt = 0; nt < 4; ++nt)
            bfr[nt] = *reinterpret_cast<const short8*>(
                &lB[cur][(wc * 64 + nt * 16 + lrow16) * 32 + pk]);
#pragma unroll
        for (int mt = 0; mt < 4; ++mt)
#pragma unroll
            for (int nt = 0; nt < 4; ++nt)
                acc[mt][nt] = __builtin_amdgcn_mfma_f32_16x16x32_bf16(
                    af[mt], bfr[nt], acc[mt][nt], 0, 0, 0);

        if ((t & 7) == 7) {                // end of a chunk: exp-epilogue
            const int ch   = t >> 3;
            const int col0 = ci * COLS_PER_SPLIT + ch * BN + wc * 64;
            const bool diagchunk = (ci * NCHUNK + ch) == bi;
            if (diagchunk) {
#pragma unroll
                for (int mt = 0; mt < 4; ++mt) {
                    const int growb = bi * BM + wr * 64 + mt * 16 + 4 * kgrp;
#pragma unroll
                    for (int r = 0; r < 4; ++r) {
                        const int grow = growb + r;
                        float s = 0.0f;
#pragma unroll
                        for (int nt = 0; nt < 4; ++nt) {
                            const int gcol = col0 + nt * 16 + lrow16;
                            float e = __expf(acc[mt][nt][r] - 2.0f);
                            s += (grow == gcol) ? 0.0f : e;
                        }
                        rowacc[mt][r] += s;
                    }
                }
            } else {
#pragma unroll
                for (int mt = 0; mt < 4; ++mt)
#pragma unroll
                    for (int r = 0; r < 4; ++r) {
                        float s = 0.0f;
#pragma unroll
                        for (int nt = 0; nt < 4; ++nt)
                            s += __expf(acc[mt][nt][r] - 2.0f);
                        rowacc[mt][r] += s;
                    }
            }
#pragma unroll
            for (int mt = 0; mt < 4; ++mt)
#pragma unroll
                for (int nt = 0; nt < 4; ++nt) acc[mt][nt] = (f32x4)(0.0f);
        }
        __syncthreads();                   // next-tile stage landed; buf reuse safe
    }

    // block-end reduce: sum over the 16 col-lanes, then combine wc pairs in LDS
#pragma unroll
    for (int mt = 0; mt < 4; ++mt)
#pragma unroll
        for (int r = 0; r < 4; ++r) {
            float v = rowacc[mt][r];
            v += __shfl_xor(v, 1); v += __shfl_xor(v, 2);
            v += __shfl_xor(v, 4); v += __shfl_xor(v, 8);
            if (lrow16 == 0) red[wid][mt * 16 + kgrp * 4 + r] = v;
        }
    __syncthreads();
    if (tid < BM) {
        const int wrr = tid >> 6, l = tid & 63;
        partials[(size_t)ci * N_TOTAL + bi * BM + tid] = red[wrr * 2][l] + red[wrr * 2 + 1][l];
    }
}

// ---------------------------------------------------------------------------
// Kernel 4a: per-row lse - pos, block-partial sums (deterministic).
// ---------------------------------------------------------------------------
__global__ __launch_bounds__(256) void lse_kernel(const float* __restrict__ partials,
                                                  const float* __restrict__ pos,
                                                  float* __restrict__ bsums) {
    int tid = threadIdx.x;
    int row = blockIdx.x * 256 + tid;
    float s = 0.0f;
#pragma unroll
    for (int c = 0; c < CSPLIT; ++c) s += partials[(size_t)c * N_TOTAL + row];
    float v = 2.0f + logf(s) - pos[row];
#pragma unroll
    for (int m = 32; m >= 1; m >>= 1) v += __shfl_xor(v, m);
    __shared__ float wsum[4];
    if ((tid & 63) == 0) wsum[tid >> 6] = v;
    __syncthreads();
    if (tid == 0) bsums[blockIdx.x] = wsum[0] + wsum[1] + wsum[2] + wsum[3];
}

__global__ void final_kernel(const float* __restrict__ bsums, float* __restrict__ out) {
    int tid = threadIdx.x;                // 64 threads
    float v = (tid < N_TOTAL / 256) ? bsums[tid] : 0.0f;
#pragma unroll
    for (int m = 32; m >= 1; m >>= 1) v += __shfl_xor(v, m);
    if (tid == 0) out[0] = v * (1.0f / (float)N_TOTAL);
}

// ---------------------------------------------------------------------------
extern "C" void kernel_launch(void* const* d_in, const int* in_sizes, int n_in,
                              void* d_out, int out_size, void* d_ws, size_t ws_size,
                              hipStream_t stream) {
    const float* z1 = (const float*)d_in[0];
    const float* z2 = (const float*)d_in[1];
    float* out = (float*)d_out;

    char* ws = (char*)d_ws;
    __hip_bfloat16* zn = (__hip_bfloat16*)ws;                              // 4 MB
    size_t off = (size_t)N_TOTAL * D_DIM * sizeof(__hip_bfloat16);
    float* pos = (float*)(ws + off);                                       // 32 KB
    off += (size_t)N_TOTAL * sizeof(float);
    float* partials = (float*)(ws + off);                                  // 512 KB
    off += (size_t)CSPLIT * N_TOTAL * sizeof(float);
    float* bsums = (float*)(ws + off);                                     // 128 B

    nrm_kernel<<<N_TOTAL / 4, 256, 0, stream>>>(z1, z2, zn);
    pos_kernel<<<B_HALF / 4, 256, 0, stream>>>(zn, pos);
    simexp_kernel<<<dim3(N_TOTAL / BM, CSPLIT), 256, 0, stream>>>(zn, partials);
    lse_kernel<<<N_TOTAL / 256, 256, 0, stream>>>(partials, pos, bsums);
    final_kernel<<<1, 64, 0, stream>>>(bsums, out);
}

// Round 4
// 50.510 us; speedup vs baseline: 2.5093x; 1.2205x over previous
//
#include <hip/hip_runtime.h>
#include <hip/hip_bf16.h>

#define N_TOTAL 8192
#define B_HALF  4096
#define D_DIM   256
#define NB      64                    // 128-row blocks
#define NPAIRS  2080                  // NB*(NB+1)/2 upper-triangle tiles
#define BK      32
#define NKT     (D_DIM / BK)          // 8 K-steps

typedef __attribute__((ext_vector_type(8))) short  short8;   // 8 x bf16
typedef __attribute__((ext_vector_type(4))) float  f32x4;

// async global->LDS, 16B per lane (dest = wave-uniform base + lane*16)
#define GLOAD16(src, dst) __builtin_amdgcn_global_load_lds( \
    (const __attribute__((address_space(1))) unsigned int*)(src), \
    (__attribute__((address_space(3))) unsigned int*)(dst), 16, 0, 0)

// ---------------------------------------------------------------------------
// Kernel 1: fused normalize + positive-pair sim.  One WAVE per pair i:
// normalizes z1[i] -> zn[i], z2[i] -> zn[i+B] (scaled by sqrt(2) so that
// bf16 dot = 2*cos = s directly), and pos[i] = 2*cos(z1_i, z2_i) in fp32
// (from unrounded inputs -> more accurate than the bf16 path).
// ---------------------------------------------------------------------------
__global__ __launch_bounds__(256) void nrmpos_kernel(const float* __restrict__ z1,
                                                     const float* __restrict__ z2,
                                                     __hip_bfloat16* __restrict__ zn,
                                                     float* __restrict__ pos) {
    int i    = (blockIdx.x * 256 + threadIdx.x) >> 6;   // pair 0..4095
    int lane = threadIdx.x & 63;
    float4 a = reinterpret_cast<const float4*>(z1 + (size_t)i * D_DIM)[lane];
    float4 b = reinterpret_cast<const float4*>(z2 + (size_t)i * D_DIM)[lane];
    float ssa = a.x * a.x + a.y * a.y + a.z * a.z + a.w * a.w;
    float ssb = b.x * b.x + b.y * b.y + b.z * b.z + b.w * b.w;
    float dab = a.x * b.x + a.y * b.y + a.z * b.z + a.w * b.w;
#pragma unroll
    for (int m = 32; m >= 1; m >>= 1) {
        ssa += __shfl_xor(ssa, m);
        ssb += __shfl_xor(ssb, m);
        dab += __shfl_xor(dab, m);
    }
    float inva = 1.0f / fmaxf(sqrtf(ssa), 1e-8f);
    float invb = 1.0f / fmaxf(sqrtf(ssb), 1e-8f);
    float sa = 1.4142135623730951f * inva;
    float sb = 1.4142135623730951f * invb;
    ushort4 oa, ob;
    { __hip_bfloat16 t = __float2bfloat16(a.x * sa); oa.x = *reinterpret_cast<unsigned short*>(&t); }
    { __hip_bfloat16 t = __float2bfloat16(a.y * sa); oa.y = *reinterpret_cast<unsigned short*>(&t); }
    { __hip_bfloat16 t = __float2bfloat16(a.z * sa); oa.z = *reinterpret_cast<unsigned short*>(&t); }
    { __hip_bfloat16 t = __float2bfloat16(a.w * sa); oa.w = *reinterpret_cast<unsigned short*>(&t); }
    { __hip_bfloat16 t = __float2bfloat16(b.x * sb); ob.x = *reinterpret_cast<unsigned short*>(&t); }
    { __hip_bfloat16 t = __float2bfloat16(b.y * sb); ob.y = *reinterpret_cast<unsigned short*>(&t); }
    { __hip_bfloat16 t = __float2bfloat16(b.z * sb); ob.z = *reinterpret_cast<unsigned short*>(&t); }
    { __hip_bfloat16 t = __float2bfloat16(b.w * sb); ob.w = *reinterpret_cast<unsigned short*>(&t); }
    reinterpret_cast<ushort4*>(zn + (size_t)i * D_DIM)[lane]            = oa;
    reinterpret_cast<ushort4*>(zn + (size_t)(i + B_HALF) * D_DIM)[lane] = ob;
    if (lane == 0) {
        float p = 2.0f * dab * inva * invb;
        pos[i]          = p;
        pos[i + B_HALF] = p;
    }
}

// ---------------------------------------------------------------------------
// Kernel 2: SYMMETRIC fused sim+exp.  One block per upper-triangle 128x128
// tile (bi,bj), bj>=bi.  exp(s-2) accumulated along BOTH axes:
//   rowacc (sum over cols) -> partials[bj][bi*128 + r]
//   colacc (sum over rows) -> partials[bi][bj*128 + c]   (off-diag only)
// For row-block R the writers {(R,bj):bj>=R} u {(bi,R):bi<R} hit slots 0..63
// exactly once each -> partials[64][8192] fully written, no memset/atomics.
// Same proven staging: linear LDS dest, source k-chunk XOR-swizzled
// (kc ^= (row>>1)&3), read-side XOR folds to per-lane const -> 0 conflicts.
// ---------------------------------------------------------------------------
__global__ __launch_bounds__(256, 4) void simexp_kernel(const __hip_bfloat16* __restrict__ zn,
                                                        float* __restrict__ partials) {
    __shared__ __attribute__((aligned(16))) __hip_bfloat16 lA[2][128 * BK];
    __shared__ __attribute__((aligned(16))) __hip_bfloat16 lB[2][128 * BK];
    __shared__ float redr[4][64];
    __shared__ float redc[4][64];

    // --- triangular decode: id -> (bi, bj), C(b) = b*(129-b)/2 ---
    const int id = blockIdx.x;
    float ff = 64.5f - sqrtf(64.5f * 64.5f - 2.0f * (float)id);
    int bi = (int)ff;
    if (bi < 0) bi = 0;
    while ((bi + 1) * (129 - (bi + 1)) / 2 <= id) ++bi;
    while (bi * (129 - bi) / 2 > id) --bi;
    const int bj = bi + (id - bi * (129 - bi) / 2);
    const bool diag = (bi == bj);

    const int tid  = threadIdx.x;
    const int lane = tid & 63;
    const int wid  = tid >> 6;
    const int wr   = wid >> 1;
    const int wc   = wid & 1;
    const int lrow16 = lane & 15;
    const int kgrp   = lane >> 4;
    const int pk = (kgrp ^ ((lrow16 >> 1) & 3)) * 8;   // swizzled k-chunk (per-lane const)

    const __hip_bfloat16* Abase = zn + (size_t)bi * 128 * D_DIM;
    const __hip_bfloat16* Bbase = zn + (size_t)bj * 128 * D_DIM;

    const int g0 = tid, g1 = tid + 256;
    const int r0 = g0 >> 2, kc0 = g0 & 3;
    const int r1 = g1 >> 2, kc1 = g1 & 3;
    const int aoff0 = r0 * D_DIM + (kc0 ^ ((r0 >> 1) & 3)) * 8;
    const int aoff1 = r1 * D_DIM + (kc1 ^ ((r1 >> 1) & 3)) * 8;

    auto stage = [&](int t, int buf) {
        const int ko = t * BK;
        GLOAD16(Abase + aoff0 + ko, &lA[buf][g0 * 8]);
        GLOAD16(Abase + aoff1 + ko, &lA[buf][g1 * 8]);
        GLOAD16(Bbase + aoff0 + ko, &lB[buf][g0 * 8]);
        GLOAD16(Bbase + aoff1 + ko, &lB[buf][g1 * 8]);
    };

    f32x4 acc[4][4];
#pragma unroll
    for (int mt = 0; mt < 4; ++mt)
#pragma unroll
        for (int nt = 0; nt < 4; ++nt) acc[mt][nt] = (f32x4)(0.0f);

    stage(0, 0);
    __syncthreads();

    for (int t = 0; t < NKT; ++t) {
        const int cur = t & 1;
        if (t + 1 < NKT) stage(t + 1, cur ^ 1);

        short8 af[4], bfr[4];
#pragma unroll
        for (int mt = 0; mt < 4; ++mt)
            af[mt] = *reinterpret_cast<const short8*>(
                &lA[cur][(wr * 64 + mt * 16 + lrow16) * BK + pk]);
#pragma unroll
        for (int nt = 0; nt < 4; ++nt)
            bfr[nt] = *reinterpret_cast<const short8*>(
                &lB[cur][(wc * 64 + nt * 16 + lrow16) * BK + pk]);
#pragma unroll
        for (int mt = 0; mt < 4; ++mt)
#pragma unroll
            for (int nt = 0; nt < 4; ++nt)
                acc[mt][nt] = __builtin_amdgcn_mfma_f32_16x16x32_bf16(
                    af[mt], bfr[nt], acc[mt][nt], 0, 0, 0);
        __syncthreads();
    }

    // --- epilogue: e = exp(s-2); both-axis accumulation ---
    float cs[4] = {0.0f, 0.0f, 0.0f, 0.0f};
#pragma unroll
    for (int mt = 0; mt < 4; ++mt) {
#pragma unroll
        for (int r = 0; r < 4; ++r) {
            float rsum = 0.0f;
            if (diag) {
                const int lrow = wr * 64 + mt * 16 + 4 * kgrp + r;
#pragma unroll
                for (int nt = 0; nt < 4; ++nt) {
                    const int lcol = wc * 64 + nt * 16 + lrow16;
                    float e = __expf(acc[mt][nt][r] - 2.0f);
                    rsum += (lrow == lcol) ? 0.0f : e;
                }
            } else {
#pragma unroll
                for (int nt = 0; nt < 4; ++nt) {
                    float e = __expf(acc[mt][nt][r] - 2.0f);
                    rsum += e;
                    cs[nt] += e;
                }
            }
            rsum += __shfl_xor(rsum, 1);
            rsum += __shfl_xor(rsum, 2);
            rsum += __shfl_xor(rsum, 4);
            rsum += __shfl_xor(rsum, 8);
            if (lrow16 == 0) redr[wid][mt * 16 + kgrp * 4 + r] = rsum;
        }
    }
    if (!diag) {
#pragma unroll
        for (int nt = 0; nt < 4; ++nt) {
            float c = cs[nt];
            c += __shfl_xor(c, 16);
            c += __shfl_xor(c, 32);
            if (kgrp == 0) redc[wid][nt * 16 + lrow16] = c;
        }
    }
    __syncthreads();

    if (tid < 128) {
        const int half = tid >> 6, l = tid & 63;
        partials[(size_t)bj * N_TOTAL + bi * 128 + tid] =
            redr[half * 2][l] + redr[half * 2 + 1][l];
        if (!diag)
            partials[(size_t)bi * N_TOTAL + bj * 128 + tid] =
                redc[half][l] + redc[half + 2][l];
    }
}

// ---------------------------------------------------------------------------
// Kernel 3: per-row lse - pos, block-partial sums (deterministic).
// ---------------------------------------------------------------------------
__global__ __launch_bounds__(256) void lse_kernel(const float* __restrict__ partials,
                                                  const float* __restrict__ pos,
                                                  float* __restrict__ bsums) {
    int tid = threadIdx.x;
    int row = blockIdx.x * 256 + tid;
    float s = 0.0f;
#pragma unroll 8
    for (int c = 0; c < NB; ++c) s += partials[(size_t)c * N_TOTAL + row];
    float v = 2.0f + logf(s) - pos[row];
#pragma unroll
    for (int m = 32; m >= 1; m >>= 1) v += __shfl_xor(v, m);
    __shared__ float wsum[4];
    if ((tid & 63) == 0) wsum[tid >> 6] = v;
    __syncthreads();
    if (tid == 0) bsums[blockIdx.x] = wsum[0] + wsum[1] + wsum[2] + wsum[3];
}

__global__ void final_kernel(const float* __restrict__ bsums, float* __restrict__ out) {
    int tid = threadIdx.x;                // 64 threads
    float v = (tid < N_TOTAL / 256) ? bsums[tid] : 0.0f;
#pragma unroll
    for (int m = 32; m >= 1; m >>= 1) v += __shfl_xor(v, m);
    if (tid == 0) out[0] = v * (1.0f / (float)N_TOTAL);
}

// ---------------------------------------------------------------------------
extern "C" void kernel_launch(void* const* d_in, const int* in_sizes, int n_in,
                              void* d_out, int out_size, void* d_ws, size_t ws_size,
                              hipStream_t stream) {
    const float* z1 = (const float*)d_in[0];
    const float* z2 = (const float*)d_in[1];
    float* out = (float*)d_out;

    char* ws = (char*)d_ws;
    __hip_bfloat16* zn = (__hip_bfloat16*)ws;                              // 4 MB
    size_t off = (size_t)N_TOTAL * D_DIM * sizeof(__hip_bfloat16);
    float* pos = (float*)(ws + off);                                       // 32 KB
    off += (size_t)N_TOTAL * sizeof(float);
    float* partials = (float*)(ws + off);                                  // 2 MB
    off += (size_t)NB * N_TOTAL * sizeof(float);
    float* bsums = (float*)(ws + off);                                     // 128 B

    nrmpos_kernel<<<B_HALF / 4, 256, 0, stream>>>(z1, z2, zn, pos);
    simexp_kernel<<<NPAIRS, 256, 0, stream>>>(zn, partials);
    lse_kernel<<<N_TOTAL / 256, 256, 0, stream>>>(partials, pos, bsums);
    final_kernel<<<1, 64, 0, stream>>>(bsums, out);
}